// Round 8
// baseline (137.793 us; speedup 1.0000x reference)
//
#include <hip/hip_runtime.h>
#include <hip/hip_bf16.h>

typedef __attribute__((ext_vector_type(8))) _Float16 half8;
typedef __attribute__((ext_vector_type(2))) _Float16 hf2;
typedef __attribute__((ext_vector_type(2))) __fp16 fp16x2;
typedef __attribute__((ext_vector_type(4))) float f32x4;
typedef __attribute__((ext_vector_type(16))) float f32x16;

union UH8 {
  half8 v;
  unsigned long long q[2];
  unsigned int w[4];
};
union U32H {
  unsigned int u;
  hf2 h;
};

__device__ __forceinline__ unsigned int pkh(float lo, float hi) {
  union { fp16x2 h; unsigned int u; } c;
  c.h = __builtin_amdgcn_cvt_pkrtz(lo, hi);
  return c.u;
}

constexpr int S_LEN = 2048;
constexpr int D_DIM = 64;
constexpr int KVB   = 64;     // kv tile rows
constexpr int QB    = 128;    // q rows per block (4 waves x 32)
constexpr int SKH   = 68;     // LDS row stride in f16 elems (136 B)
constexpr int TILE  = 64 * SKH;
constexpr int NT    = S_LEN / KVB;
constexpr float LOG2E = 1.4426950408889634f;
constexpr float INV_D_QTR = 0.35355339059327373f;  // 1 / 64^0.25
constexpr float THR = 4.0f;   // defer-max threshold: P <= e^4 = 54.6, fp16-safe

__global__ __launch_bounds__(256) void attn_fwd(
    const float* __restrict__ Q, const float* __restrict__ K,
    const float* __restrict__ V, float* __restrict__ O)
{
  const int tid  = threadIdx.x;
  const int w    = tid >> 6;      // wave 0..3
  const int lane = tid & 63;
  const int q32  = lane & 31;     // q-row within wave tile / MFMA m,n index
  const int h    = lane >> 5;     // half-wave index

  // XCD-aware bijective swizzle (1024 = 8 x 128)
  const int bid = blockIdx.x;
  const int wg  = (bid & 7) * 128 + (bid >> 3);
  const int qb  = wg & 15;        // q-block within head
  const int bh  = wg >> 4;        // batch*head

  const int q0 = qb * QB;

  __shared__ unsigned short Ks[TILE];  // K tile [kv][d] f16, single buffer
  __shared__ unsigned short Vt[TILE];  // V^T tile [d][kv] f16, single buffer

  const size_t base = (size_t)bh * S_LEN * D_DIM;

  // ---- staging ownership ----
  const int kr = tid >> 3;             // K row 0..31 (and +32)
  const int kc = (tid & 7) * 8;        // K col elem offset

  float4 ka0, kb0, ka1, kb1;
  float va[8], vb[8];

  auto PREF = [&](int tt) {
    const int kv0 = tt * KVB;
    const float* kp = K + base + (size_t)(kv0 + kr) * D_DIM + kc;
    ka0 = *(const float4*)kp;
    kb0 = *(const float4*)(kp + 4);
    const float* kp1 = kp + 32 * D_DIM;
    ka1 = *(const float4*)kp1;
    kb1 = *(const float4*)(kp1 + 4);
    const float* vp = V + base + (size_t)(kv0 + w * 16) * D_DIM + lane;
    #pragma unroll
    for (int p = 0; p < 8; ++p) {
      va[p] = vp[(2 * p) * D_DIM];
      vb[p] = vp[(2 * p + 1) * D_DIM];
    }
  };

  auto WRITE = [&]() {
    *(unsigned long long*)&Ks[kr * SKH + kc] =
        (unsigned long long)pkh(ka0.x, ka0.y) | ((unsigned long long)pkh(ka0.z, ka0.w) << 32);
    *(unsigned long long*)&Ks[kr * SKH + kc + 4] =
        (unsigned long long)pkh(kb0.x, kb0.y) | ((unsigned long long)pkh(kb0.z, kb0.w) << 32);
    *(unsigned long long*)&Ks[(kr + 32) * SKH + kc] =
        (unsigned long long)pkh(ka1.x, ka1.y) | ((unsigned long long)pkh(ka1.z, ka1.w) << 32);
    *(unsigned long long*)&Ks[(kr + 32) * SKH + kc + 4] =
        (unsigned long long)pkh(kb1.x, kb1.y) | ((unsigned long long)pkh(kb1.z, kb1.w) << 32);
    #pragma unroll
    for (int p = 0; p < 8; ++p)
      *(unsigned int*)&Vt[lane * SKH + w * 16 + 2 * p] = pkh(va[p], vb[p]);
  };

  // ---- Q fragments fp16: qf[s] holds Q[q32][k = s*16 + h*8 + j], j=0..7 ----
  UH8 qf[4];
  {
    const float* qp = Q + base + (size_t)(q0 + w * 32 + q32) * D_DIM;
    #pragma unroll
    for (int s = 0; s < 4; ++s) {
      float4 a = *(const float4*)(qp + s * 16 + h * 8);
      float4 b = *(const float4*)(qp + s * 16 + h * 8 + 4);
      qf[s].w[0] = pkh(a.x, a.y);
      qf[s].w[1] = pkh(a.z, a.w);
      qf[s].w[2] = pkh(b.x, b.y);
      qf[s].w[3] = pkh(b.z, b.w);
    }
  }

  // O^T accum: oc[dt] reg r -> O[d = dt*32 + (r&3) + 8*(r>>2) + 4h][q = q32]
  f32x16 oc[2] = {
    {0,0,0,0,0,0,0,0,0,0,0,0,0,0,0,0},
    {0,0,0,0,0,0,0,0,0,0,0,0,0,0,0,0}
  };
  float mrow = -1e30f;
  float lrow = 0.f;

  const U32H one = {0x3C003C00u};   // (1.0h, 1.0h)

  PREF(0);
  WRITE();
  __syncthreads();

  for (int t = 0; t < NT; ++t) {
    const bool more = (t + 1 < NT);
    if (more) PREF(t + 1);     // global loads in flight across compute phase

    // ---- swapped QK^T (32x32x16): sc[kvt] reg r = S[kv = kvt*32+(r&3)+8*(r>>2)+4h][q32]
    f32x16 sc[2];
    __builtin_amdgcn_s_setprio(1);
    #pragma unroll
    for (int kvt = 0; kvt < 2; ++kvt) {
      f32x16 acc = {0,0,0,0,0,0,0,0,0,0,0,0,0,0,0,0};
      #pragma unroll
      for (int s = 0; s < 4; ++s) {
        UH8 af;
        const int off = (kvt * 32 + q32) * SKH + s * 16 + h * 8;
        af.q[0] = *(const unsigned long long*)&Ks[off];
        af.q[1] = *(const unsigned long long*)&Ks[off + 4];
        acc = __builtin_amdgcn_mfma_f32_32x32x16_f16(af.v, qf[s].v, acc, 0, 0, 0);
      }
      sc[kvt] = acc;
    }
    __builtin_amdgcn_s_setprio(0);

    // ---- tile max, tree-form (max3-fusable, short dep chain) ----
    float u[8];
    #pragma unroll
    for (int j = 0; j < 8; ++j)
      u[j] = fmaxf(fmaxf(sc[0][j], sc[0][j + 8]), fmaxf(sc[1][j], sc[1][j + 8]));
    #pragma unroll
    for (int j = 0; j < 4; ++j) u[j] = fmaxf(u[j], u[j + 4]);
    float pm = fmaxf(fmaxf(u[0], u[2]), fmaxf(u[1], u[3]));
    pm = fmaxf(pm, __shfl_xor(pm, 32, 64));

    // ---- defer-max: rescale only when some row's max grew past THR ----
    if (__any(pm - mrow > THR)) {
      const float mnew = fmaxf(mrow, pm);
      const float corr = __builtin_amdgcn_exp2f((mrow - mnew) * LOG2E);
      #pragma unroll
      for (int dt = 0; dt < 2; ++dt)
        #pragma unroll
        for (int i = 0; i < 16; ++i)
          oc[dt][i] *= corr;
      lrow *= corr;
      mrow = mnew;
    }

    // ---- exp (args <= THR by construction) ----
    #pragma unroll
    for (int kvt = 0; kvt < 2; ++kvt)
      #pragma unroll
      for (int i = 0; i < 16; ++i)
        sc[kvt][i] = __builtin_amdgcn_exp2f((sc[kvt][i] - mrow) * LOG2E);

    // ---- swapped PV (32x32x16) + row-sum via fdot2 on the same fp16 packs ----
    float ps = 0.f;
    #pragma unroll
    for (int s = 0; s < 4; ++s) {
      const int kvt = s >> 1;
      const int sr  = (s & 1) * 8;
      unsigned int LO0 = pkh(sc[kvt][sr + 0], sc[kvt][sr + 1]);
      unsigned int LO1 = pkh(sc[kvt][sr + 2], sc[kvt][sr + 3]);
      unsigned int HI0 = pkh(sc[kvt][sr + 4], sc[kvt][sr + 5]);
      unsigned int HI1 = pkh(sc[kvt][sr + 6], sc[kvt][sr + 7]);
      U32H c0 = {LO0}, c1 = {LO1}, c2 = {HI0}, c3 = {HI1};
      ps = __builtin_amdgcn_fdot2(c0.h, one.h, ps, false);
      ps = __builtin_amdgcn_fdot2(c1.h, one.h, ps, false);
      ps = __builtin_amdgcn_fdot2(c2.h, one.h, ps, false);
      ps = __builtin_amdgcn_fdot2(c3.h, one.h, ps, false);
      // v_permlane32_swap_b32 vdst, vsrc: vdst's HIGH 32 lanes <-> vsrc's LOW 32 lanes.
      asm("v_permlane32_swap_b32 %0, %1" : "+v"(LO0), "+v"(HI0));
      asm("v_permlane32_swap_b32 %0, %1" : "+v"(LO1), "+v"(HI1));
      UH8 pf;
      pf.w[0] = LO0;
      pf.w[1] = LO1;
      pf.w[2] = HI0;
      pf.w[3] = HI1;
      __builtin_amdgcn_s_setprio(1);
      #pragma unroll
      for (int dt = 0; dt < 2; ++dt) {
        UH8 vf;
        const int off = (dt * 32 + q32) * SKH + s * 16 + h * 8;
        vf.q[0] = *(const unsigned long long*)&Vt[off];
        vf.q[1] = *(const unsigned long long*)&Vt[off + 4];
        oc[dt] = __builtin_amdgcn_mfma_f32_32x32x16_f16(vf.v, pf.v, oc[dt], 0, 0, 0);
      }
      __builtin_amdgcn_s_setprio(0);
    }
    ps += __shfl_xor(ps, 32, 64);
    lrow += ps;

    __syncthreads();           // all reads of tile t done
    if (more) {
      WRITE();                 // stage tile t+1 (vmcnt waits land here)
      __syncthreads();         // staged before next compute
    }
  }

  // ---- epilogue: O[q][d] = oc * (dim^-0.25 / l) ----
  const float inv = INV_D_QTR / lrow;
  float* orow = O + base + (size_t)(q0 + w * 32 + q32) * D_DIM;
  #pragma unroll
  for (int dt = 0; dt < 2; ++dt)
    #pragma unroll
    for (int r1 = 0; r1 < 4; ++r1) {
      f32x4 o = { oc[dt][4 * r1 + 0] * inv, oc[dt][4 * r1 + 1] * inv,
                  oc[dt][4 * r1 + 2] * inv, oc[dt][4 * r1 + 3] * inv };
      *(f32x4*)(orow + dt * 32 + 8 * r1 + 4 * h) = o;
    }
}

extern "C" void kernel_launch(void* const* d_in, const int* in_sizes, int n_in,
                              void* d_out, int out_size, void* d_ws, size_t ws_size,
                              hipStream_t stream) {
  const float* q = (const float*)d_in[0];
  const float* k = (const float*)d_in[1];
  const float* v = (const float*)d_in[2];
  float* o = (float*)d_out;
  const int nblocks = (S_LEN / QB) * 64;   // 16 q-blocks x 64 bh = 1024
  attn_fwd<<<dim3(nblocks), dim3(256), 0, stream>>>(q, k, v, o);
}

// Round 9
// 125.125 us; speedup vs baseline: 1.1012x; 1.1012x over previous
//
#include <hip/hip_runtime.h>
#include <hip/hip_bf16.h>

typedef __attribute__((ext_vector_type(8))) _Float16 half8;
typedef __attribute__((ext_vector_type(2))) _Float16 hf2;
typedef __attribute__((ext_vector_type(2))) __fp16 fp16x2;
typedef __attribute__((ext_vector_type(4))) float f32x4;
typedef __attribute__((ext_vector_type(16))) float f32x16;

union UH8 {
  half8 v;
  unsigned long long q[2];
  unsigned int w[4];
};
union U32H {
  unsigned int u;
  hf2 h;
};

__device__ __forceinline__ unsigned int pkh(float lo, float hi) {
  union { fp16x2 h; unsigned int u; } c;
  c.h = __builtin_amdgcn_cvt_pkrtz(lo, hi);
  return c.u;
}

constexpr int S_LEN = 2048;
constexpr int D_DIM = 64;
constexpr int KVB   = 64;     // kv tile rows
constexpr int QB    = 128;    // q rows per block (4 waves x 32)
constexpr int SKH   = 68;     // LDS row stride in f16 elems (136 B): rows 2-way-alias banks (free)
constexpr int TILE  = 64 * SKH;
constexpr int NT    = S_LEN / KVB;
constexpr float LOG2E = 1.4426950408889634f;
constexpr float INV_D_QTR = 0.35355339059327373f;  // 1 / 64^0.25
constexpr float THR_L2 = 6.0f;   // defer-max threshold in log2 units: P <= 2^6 = 64, fp16-safe

__global__ __launch_bounds__(256) void attn_fwd(
    const float* __restrict__ Q, const float* __restrict__ K,
    const float* __restrict__ V, float* __restrict__ O)
{
  const int tid  = threadIdx.x;
  const int w    = tid >> 6;      // wave 0..3
  const int lane = tid & 63;
  const int q32  = lane & 31;     // q-row within wave tile / MFMA m,n index
  const int h    = lane >> 5;     // half-wave index

  // XCD-aware bijective swizzle (1024 = 8 x 128)
  const int bid = blockIdx.x;
  const int wg  = (bid & 7) * 128 + (bid >> 3);
  const int qb  = wg & 15;        // q-block within head
  const int bh  = wg >> 4;        // batch*head

  const int q0 = qb * QB;

  __shared__ unsigned short KsB[2][TILE];  // K tile [kv][d] f16, double-buffered
  __shared__ unsigned short VtB[2][TILE];  // V^T tile [d][kv] f16, double-buffered

  const size_t base = (size_t)bh * S_LEN * D_DIM;

  // ---- staging ownership ----
  const int kr = tid >> 3;             // K row 0..31 (and +32)
  const int kc = (tid & 7) * 8;        // K col elem offset

  float4 ka0, kb0, ka1, kb1;
  float va[8], vb[8];

  auto PREF = [&](int tt) {
    const int kv0 = tt * KVB;
    const float* kp = K + base + (size_t)(kv0 + kr) * D_DIM + kc;
    ka0 = *(const float4*)kp;
    kb0 = *(const float4*)(kp + 4);
    const float* kp1 = kp + 32 * D_DIM;
    ka1 = *(const float4*)kp1;
    kb1 = *(const float4*)(kp1 + 4);
    const float* vp = V + base + (size_t)(kv0 + w * 16) * D_DIM + lane;
    #pragma unroll
    for (int p = 0; p < 8; ++p) {
      va[p] = vp[(2 * p) * D_DIM];
      vb[p] = vp[(2 * p + 1) * D_DIM];
    }
  };

  auto WRITE = [&](int b) {
    unsigned short* kd = KsB[b];
    *(unsigned long long*)&kd[kr * SKH + kc] =
        (unsigned long long)pkh(ka0.x, ka0.y) | ((unsigned long long)pkh(ka0.z, ka0.w) << 32);
    *(unsigned long long*)&kd[kr * SKH + kc + 4] =
        (unsigned long long)pkh(kb0.x, kb0.y) | ((unsigned long long)pkh(kb0.z, kb0.w) << 32);
    *(unsigned long long*)&kd[(kr + 32) * SKH + kc] =
        (unsigned long long)pkh(ka1.x, ka1.y) | ((unsigned long long)pkh(ka1.z, ka1.w) << 32);
    *(unsigned long long*)&kd[(kr + 32) * SKH + kc + 4] =
        (unsigned long long)pkh(kb1.x, kb1.y) | ((unsigned long long)pkh(kb1.z, kb1.w) << 32);
    unsigned short* vd = VtB[b];
    #pragma unroll
    for (int p = 0; p < 4; ++p) {     // merged: elems 4p..4p+3 contiguous -> b64 writes
      const unsigned long long lohi =
          (unsigned long long)pkh(va[2 * p], vb[2 * p]) |
          ((unsigned long long)pkh(va[2 * p + 1], vb[2 * p + 1]) << 32);
      *(unsigned long long*)&vd[lane * SKH + w * 16 + 4 * p] = lohi;
    }
  };

  // ---- Q fragments fp16, pre-scaled by LOG2E: scores come out in log2 units ----
  UH8 qf[4];
  {
    const float* qp = Q + base + (size_t)(q0 + w * 32 + q32) * D_DIM;
    #pragma unroll
    for (int s = 0; s < 4; ++s) {
      float4 a = *(const float4*)(qp + s * 16 + h * 8);
      float4 b = *(const float4*)(qp + s * 16 + h * 8 + 4);
      qf[s].w[0] = pkh(a.x * LOG2E, a.y * LOG2E);
      qf[s].w[1] = pkh(a.z * LOG2E, a.w * LOG2E);
      qf[s].w[2] = pkh(b.x * LOG2E, b.y * LOG2E);
      qf[s].w[3] = pkh(b.z * LOG2E, b.w * LOG2E);
    }
  }

  // O^T accum: oc[dt] reg r -> O[d = dt*32 + (r&3) + 8*(r>>2) + 4h][q = q32]
  f32x16 oc[2] = {
    {0,0,0,0,0,0,0,0,0,0,0,0,0,0,0,0},
    {0,0,0,0,0,0,0,0,0,0,0,0,0,0,0,0}
  };
  float mrow = -1e30f;   // running max in log2 units
  float lrow = 0.f;

  const U32H one = {0x3C003C00u};   // (1.0h, 1.0h)

  PREF(0);
  WRITE(0);

  for (int t = 0; t < NT; ++t) {
    const bool more = (t + 1 < NT);
    if (more) PREF(t + 1);     // loads in flight across the whole compute phase
    __syncthreads();
    const int cb = t & 1;
    const unsigned short* ksc = KsB[cb];
    const unsigned short* vtc = VtB[cb];

    // ---- swapped QK^T (32x32x16): sc[kvt] reg r = S[kv = kvt*32+(r&3)+8*(r>>2)+4h][q32]
    f32x16 sc[2];
    __builtin_amdgcn_s_setprio(1);
    #pragma unroll
    for (int kvt = 0; kvt < 2; ++kvt) {
      f32x16 acc = {0,0,0,0,0,0,0,0,0,0,0,0,0,0,0,0};
      #pragma unroll
      for (int s = 0; s < 4; ++s) {
        UH8 af;
        const int off = (kvt * 32 + q32) * SKH + s * 16 + h * 8;
        af.q[0] = *(const unsigned long long*)&ksc[off];
        af.q[1] = *(const unsigned long long*)&ksc[off + 4];
        acc = __builtin_amdgcn_mfma_f32_32x32x16_f16(af.v, qf[s].v, acc, 0, 0, 0);
      }
      sc[kvt] = acc;
    }
    __builtin_amdgcn_s_setprio(0);

    // ---- tile max, tree-form ----
    float u[8];
    #pragma unroll
    for (int j = 0; j < 8; ++j)
      u[j] = fmaxf(fmaxf(sc[0][j], sc[0][j + 8]), fmaxf(sc[1][j], sc[1][j + 8]));
    #pragma unroll
    for (int j = 0; j < 4; ++j) u[j] = fmaxf(u[j], u[j + 4]);
    float pm = fmaxf(fmaxf(u[0], u[2]), fmaxf(u[1], u[3]));
    pm = fmaxf(pm, __shfl_xor(pm, 32, 64));

    // ---- defer-max: rescale only when some row's max grew past THR_L2 ----
    if (__any(pm - mrow > THR_L2)) {
      const float mnew = fmaxf(mrow, pm);
      const float corr = __builtin_amdgcn_exp2f(mrow - mnew);
      #pragma unroll
      for (int dt = 0; dt < 2; ++dt)
        #pragma unroll
        for (int i = 0; i < 16; ++i)
          oc[dt][i] *= corr;
      lrow *= corr;
      mrow = mnew;
    }

    // ---- exp2 (args <= THR_L2 by construction; scores already log2-scaled) ----
    #pragma unroll
    for (int kvt = 0; kvt < 2; ++kvt)
      #pragma unroll
      for (int i = 0; i < 16; ++i)
        sc[kvt][i] = __builtin_amdgcn_exp2f(sc[kvt][i] - mrow);

    // ---- swapped PV (32x32x16) + row-sum via fdot2 on the same fp16 packs ----
    float ps = 0.f;
    __builtin_amdgcn_s_setprio(1);
    #pragma unroll
    for (int s = 0; s < 4; ++s) {
      const int kvt = s >> 1;
      const int sr  = (s & 1) * 8;
      unsigned int LO0 = pkh(sc[kvt][sr + 0], sc[kvt][sr + 1]);
      unsigned int LO1 = pkh(sc[kvt][sr + 2], sc[kvt][sr + 3]);
      unsigned int HI0 = pkh(sc[kvt][sr + 4], sc[kvt][sr + 5]);
      unsigned int HI1 = pkh(sc[kvt][sr + 6], sc[kvt][sr + 7]);
      U32H c0 = {LO0}, c1 = {LO1}, c2 = {HI0}, c3 = {HI1};
      ps = __builtin_amdgcn_fdot2(c0.h, one.h, ps, false);
      ps = __builtin_amdgcn_fdot2(c1.h, one.h, ps, false);
      ps = __builtin_amdgcn_fdot2(c2.h, one.h, ps, false);
      ps = __builtin_amdgcn_fdot2(c3.h, one.h, ps, false);
      // v_permlane32_swap_b32 vdst, vsrc: vdst's HIGH 32 lanes <-> vsrc's LOW 32 lanes.
      asm("v_permlane32_swap_b32 %0, %1" : "+v"(LO0), "+v"(HI0));
      asm("v_permlane32_swap_b32 %0, %1" : "+v"(LO1), "+v"(HI1));
      UH8 pf;
      pf.w[0] = LO0;
      pf.w[1] = LO1;
      pf.w[2] = HI0;
      pf.w[3] = HI1;
      #pragma unroll
      for (int dt = 0; dt < 2; ++dt) {
        UH8 vf;
        const int off = (dt * 32 + q32) * SKH + s * 16 + h * 8;
        vf.q[0] = *(const unsigned long long*)&vtc[off];
        vf.q[1] = *(const unsigned long long*)&vtc[off + 4];
        oc[dt] = __builtin_amdgcn_mfma_f32_32x32x16_f16(vf.v, pf.v, oc[dt], 0, 0, 0);
      }
    }
    __builtin_amdgcn_s_setprio(0);
    ps += __shfl_xor(ps, 32, 64);
    lrow += ps;

    if (more) WRITE(1 - cb);   // loads have had the whole compute phase to land
  }

  // ---- epilogue: O[q][d] = oc * (dim^-0.25 / l) ----
  const float inv = INV_D_QTR / lrow;
  float* orow = O + base + (size_t)(q0 + w * 32 + q32) * D_DIM;
  #pragma unroll
  for (int dt = 0; dt < 2; ++dt)
    #pragma unroll
    for (int r1 = 0; r1 < 4; ++r1) {
      f32x4 o = { oc[dt][4 * r1 + 0] * inv, oc[dt][4 * r1 + 1] * inv,
                  oc[dt][4 * r1 + 2] * inv, oc[dt][4 * r1 + 3] * inv };
      *(f32x4*)(orow + dt * 32 + 8 * r1 + 4 * h) = o;
    }
}

extern "C" void kernel_launch(void* const* d_in, const int* in_sizes, int n_in,
                              void* d_out, int out_size, void* d_ws, size_t ws_size,
                              hipStream_t stream) {
  const float* q = (const float*)d_in[0];
  const float* k = (const float*)d_in[1];
  const float* v = (const float*)d_in[2];
  float* o = (float*)d_out;
  const int nblocks = (S_LEN / QB) * 64;   // 16 q-blocks x 64 bh = 1024
  attn_fwd<<<dim3(nblocks), dim3(256), 0, stream>>>(q, k, v, o);
}